// Round 1
// baseline (252.810 us; speedup 1.0000x reference)
//
#include <hip/hip_runtime.h>

// Problem constants (from reference setup_inputs):
//   fm0: [16,3,80,80,85]  -> 26,112,000 floats, 19200 rows/batch, scale 80
//   fm1: [16,3,40,40,85]  ->  6,528,000 floats,  4800 rows/batch, scale 40
//   fm2: [16,3,20,20,85]  ->  1,632,000 floats,  1200 rows/batch, scale 20
//   out: [16, 25200, 85]  -> 34,272,000 floats
#define NB        16
#define NROWS_OUT 25200
#define L0_FLOATS 26112000
#define L1_FLOATS 6528000
#define L2_FLOATS 1632000
#define TOTAL_FLOATS (L0_FLOATS + L1_FLOATS + L2_FLOATS)   // 34,272,000
#define TOTAL4 (TOTAL_FLOATS / 4)                          //  8,568,000

__device__ __forceinline__ float sigmoidf(float x) {
    return 1.0f / (1.0f + __expf(-x));
}

// Process one aligned float4 from a level's flat input buffer.
// ROWS = rows per batch in this level, OFF = row offset of this level in the
// output's N dimension, SCALE = W (== H, maps are square).
//
// Alignment proof: f_local is a multiple of 4; out_f = f_local +
// (b*(NROWS_OUT-ROWS) + OFF)*85, and (NROWS_OUT-ROWS)*85 and OFF*85 are
// multiples of 4 for all three levels -> out_f is a multiple of 4, so both
// the load and the store are 16B-aligned.
template <int ROWS, int OFF, int SCALE>
__device__ __forceinline__ void process4(const float* __restrict__ in,
                                         float* __restrict__ out,
                                         int f_local) {
    constexpr int ROWS85 = ROWS * 85;
    const int b   = f_local / ROWS85;          // magic-mul (const divisor)
    const int rem = f_local - b * ROWS85;      // j*85 + c within batch
    const int c0  = rem % 85;                  // channel of first element
    const float* src = in + f_local;
    const float4 x = *(const float4*)src;
    const int out_f = (b * NROWS_OUT + OFF) * 85 + rem;

    float xv[4] = {x.x, x.y, x.z, x.w};
    float y[4];
#pragma unroll
    for (int k = 0; k < 4; ++k) {
        int c = c0 + k;
        if (c >= 85) c -= 85;                  // at most one row wrap per float4
        if (c >= 4) {
            y[k] = sigmoidf(xv[k]);            // conf + class channels
        } else {
            // Box channels: need (b0,b1,b2,b3) of this row. Row start is at
            // src + (k - c). These re-reads hit L1 (same/adjacent cache line).
            const float* row = src + (k - c);
            const float b0 = row[0], b1 = row[1], b2 = row[2], b3 = row[3];
            const float h2 = 0.5f * b2, h3 = 0.5f * b3;
            const float sc = (float)SCALE;
            const float x1 = (b0 - h2) * sc;
            const float y1 = (b1 - h3) * sc;
            float r;
            if (c == 0)      r = x1;
            else if (c == 1) r = y1;
            else if (c == 2) r = (x1 + h2) * sc;
            else             r = (y1 + h3) * sc;
            y[k] = r;
        }
    }
    *(float4*)(out + out_f) = make_float4(y[0], y[1], y[2], y[3]);
}

__global__ __launch_bounds__(256) void yolo_decode_kernel(
    const float* __restrict__ fm0, const float* __restrict__ fm1,
    const float* __restrict__ fm2, float* __restrict__ out) {
    const int v = blockIdx.x * 256 + threadIdx.x;
    if (v >= TOTAL4) return;
    const int f = v * 4;  // flat float index across concatenated levels
    if (f < L0_FLOATS) {
        process4<19200, 0, 80>(fm0, out, f);
    } else if (f < L0_FLOATS + L1_FLOATS) {
        process4<4800, 19200, 40>(fm1, out, f - L0_FLOATS);
    } else {
        process4<1200, 24000, 20>(fm2, out, f - (L0_FLOATS + L1_FLOATS));
    }
}

extern "C" void kernel_launch(void* const* d_in, const int* in_sizes, int n_in,
                              void* d_out, int out_size, void* d_ws, size_t ws_size,
                              hipStream_t stream) {
    const float* fm0 = (const float*)d_in[0];
    const float* fm1 = (const float*)d_in[1];
    const float* fm2 = (const float*)d_in[2];
    // d_in[3] (detection_targets) is unused by the reference output.
    float* out = (float*)d_out;

    const int blocks = (TOTAL4 + 255) / 256;  // 33,469
    hipLaunchKernelGGL(yolo_decode_kernel, dim3(blocks), dim3(256), 0, stream,
                       fm0, fm1, fm2, out);
}

// Round 3
// 236.962 us; speedup vs baseline: 1.0669x; 1.0669x over previous
//
#include <hip/hip_runtime.h>

// Problem constants (from reference setup_inputs):
//   fm0: [16,3,80,80,85]  -> 26,112,000 floats, 19200 rows/batch, scale 80
//   fm1: [16,3,40,40,85]  ->  6,528,000 floats,  4800 rows/batch, scale 40
//   fm2: [16,3,20,20,85]  ->  1,632,000 floats,  1200 rows/batch, scale 20
//   out: [16, 25200, 85]  -> 34,272,000 floats
#define NROWS_OUT 25200
#define L0_FLOATS 26112000
#define L1_FLOATS 6528000
#define L2_FLOATS 1632000
#define TOTAL_FLOATS (L0_FLOATS + L1_FLOATS + L2_FLOATS)   // 34,272,000
#define TOTAL4   (TOTAL_FLOATS / 4)                        //  8,568,000
#define HALF4    (TOTAL4 / 2)                              //  4,284,000

typedef float v4f __attribute__((ext_vector_type(4)));     // native vec for NT store

__device__ __forceinline__ float fast_sigmoid(float x) {
    // v_exp_f32 (+1 mul) + v_rcp_f32: ~4 VALU ops, rel err ~1e-6.
    float e = __expf(-x);
    return __builtin_amdgcn_rcpf(1.0f + e);
}

// Branchless processing of one aligned float4 from a level's flat buffer.
// ROWS/OFF/SCALE are per-level compile-time constants.
//
// Alignment: f_local % 4 == 0, and the output shift per (b,level) is a
// multiple of 4 floats for all levels, so load and store are 16B-aligned.
//
// Box handling: channels 0..3 of at most ONE row intersect this float4
// (c0<=3 XOR c0>=82). Its row start g is computed unconditionally (dummy =
// own address when absent) and the 4 row floats are loaded up-front in the
// same batch as the main float4 — no divergent in-branch loads.
template <int ROWS, int OFF, int SCALE>
__device__ __forceinline__ void process4(const float* __restrict__ in,
                                         float* __restrict__ out,
                                         int f_local) {
    constexpr int ROWS85 = ROWS * 85;
    const int b   = f_local / ROWS85;          // magic-mul (const divisor)
    const int rem = f_local - b * ROWS85;      // j*85 + c within batch
    const int c0  = rem % 85;                  // channel of first element

    // Box row start (flat index in this level's buffer); dummy when no box.
    int g = f_local;
    if (c0 <= 3)  g = f_local - c0;            // row began at/just before us
    if (c0 >= 82) g = f_local + (85 - c0);     // next row begins inside us
    // (c0<=3 and c0>=82 are mutually exclusive; g stays in-bounds: buffers
    //  are whole rows, and c0>=82 implies the next row exists in full.)

    const v4f x = *(const v4f*)(in + f_local);
    const float r0 = in[g + 0];
    const float r1 = in[g + 1];
    const float r2 = in[g + 2];
    const float r3 = in[g + 3];

    const float sc = (float)SCALE;
    const float h2 = 0.5f * r2, h3 = 0.5f * r3;
    const float q0 = (r0 - h2) * sc;           // x1
    const float q1 = (r1 - h3) * sc;           // y1
    const float q2 = (q0 + h2) * sc;           // x2
    const float q3 = (q1 + h3) * sc;           // y2

    float xv[4] = {x.x, x.y, x.z, x.w};
    float y[4];
#pragma unroll
    for (int k = 0; k < 4; ++k) {
        int c = c0 + k;
        if (c >= 85) c -= 85;                  // at most one row wrap
        const float s = fast_sigmoid(xv[k]);
        const float q = (c == 0) ? q0 : ((c == 1) ? q1 : ((c == 2) ? q2 : q3));
        y[k] = (c < 4) ? q : s;                // v_cndmask chain, no branch
    }

    const int out_f = (b * NROWS_OUT + OFF) * 85 + rem;
    v4f yo; yo.x = y[0]; yo.y = y[1]; yo.z = y[2]; yo.w = y[3];
    __builtin_nontemporal_store(yo, (v4f*)(out + out_f));
}

__device__ __forceinline__ void dispatch4(const float* __restrict__ fm0,
                                          const float* __restrict__ fm1,
                                          const float* __restrict__ fm2,
                                          float* __restrict__ out, int f) {
    if (f < L0_FLOATS) {
        process4<19200, 0, 80>(fm0, out, f);
    } else if (f < L0_FLOATS + L1_FLOATS) {
        process4<4800, 19200, 40>(fm1, out, f - L0_FLOATS);
    } else {
        process4<1200, 24000, 20>(fm2, out, f - (L0_FLOATS + L1_FLOATS));
    }
}

__global__ __launch_bounds__(256) void yolo_decode_kernel(
    const float* __restrict__ fm0, const float* __restrict__ fm1,
    const float* __restrict__ fm2, float* __restrict__ out) {
    const int v = blockIdx.x * 256 + threadIdx.x;
    if (v >= HALF4) return;
    // Two independent float4s per thread (memory ILP); both halves stay
    // coalesced: consecutive lanes -> consecutive float4s.
    dispatch4(fm0, fm1, fm2, out, v * 4);
    dispatch4(fm0, fm1, fm2, out, (v + HALF4) * 4);
}

extern "C" void kernel_launch(void* const* d_in, const int* in_sizes, int n_in,
                              void* d_out, int out_size, void* d_ws, size_t ws_size,
                              hipStream_t stream) {
    const float* fm0 = (const float*)d_in[0];
    const float* fm1 = (const float*)d_in[1];
    const float* fm2 = (const float*)d_in[2];
    float* out = (float*)d_out;

    const int blocks = (HALF4 + 255) / 256;  // 16,735
    hipLaunchKernelGGL(yolo_decode_kernel, dim3(blocks), dim3(256), 0, stream,
                       fm0, fm1, fm2, out);
}